// Round 12
// baseline (194.032 us; speedup 1.0000x reference)
//
#include <hip/hip_runtime.h>
#include <stdint.h>

#define B_  4
#define S_  2048
#define D_  1024
#define H_  16
#define HD_ 64

typedef __attribute__((ext_vector_type(8))) short bf16x8;
typedef __attribute__((ext_vector_type(4))) short bf16x4;
typedef __attribute__((ext_vector_type(4))) float f32x4;

#define MFMA32(a, b, c) __builtin_amdgcn_mfma_f32_16x16x32_bf16(a, b, c, 0, 0, 0)

__device__ __forceinline__ unsigned short f2bf(float f) {
  union { float f; uint32_t u; } cv; cv.f = f;
  uint32_t x = cv.u;
  uint32_t r = (x + 0x7fffu + ((x >> 16) & 1u)) >> 16;  // RNE
  return (unsigned short)r;
}

__device__ __forceinline__ float fexp2(float x) {
#if __has_builtin(__builtin_amdgcn_exp2f)
  return __builtin_amdgcn_exp2f(x);   // native v_exp_f32 (2^x)
#else
  return exp2f(x);
#endif
}

// pack two f32 -> two bf16 (truncate) in one v_perm_b32
__device__ __forceinline__ uint32_t pk2(float lo, float hi) {
  union { float f; uint32_t u; } a, b;
  a.f = lo; b.f = hi;
#if __has_builtin(__builtin_amdgcn_perm)
  return __builtin_amdgcn_perm(b.u, a.u, 0x07060302u);
#else
  return (b.u & 0xffff0000u) | (a.u >> 16);
#endif
}

__device__ __forceinline__ void gload_lds16(const unsigned short* g, unsigned short* l) {
  __builtin_amdgcn_global_load_lds((const __attribute__((address_space(1))) void*)g,
                                   (__attribute__((address_space(3))) void*)l, 16, 0, 0);
}

// ---------- prep: x fp32 -> bf16 ----------
__global__ void k_cast_x(const float* __restrict__ x, unsigned short* __restrict__ xb) {
  size_t i = ((size_t)blockIdx.x * 256 + threadIdx.x) * 8;
  float4 a = *(const float4*)(x + i);
  float4 b = *(const float4*)(x + i + 4);
  bf16x8 o;
  o[0] = (short)f2bf(a.x); o[1] = (short)f2bf(a.y);
  o[2] = (short)f2bf(a.z); o[3] = (short)f2bf(a.w);
  o[4] = (short)f2bf(b.x); o[5] = (short)f2bf(b.y);
  o[6] = (short)f2bf(b.z); o[7] = (short)f2bf(b.w);
  *(bf16x8*)(xb + i) = o;
}

// ---------- prep: Wq/Wk/Wv [H,D,HD] -> W1T [3072][1024] ----------
__global__ void k_wqkv_t(const float* __restrict__ Wq, const float* __restrict__ Wk,
                         const float* __restrict__ Wv, unsigned short* __restrict__ W1T) {
  __shared__ unsigned short tile[64][65];
  const float* W = (blockIdx.z == 0) ? Wq : (blockIdx.z == 1) ? Wk : Wv;
  int h = blockIdx.y;
  int d0 = blockIdx.x * 64;
  int tx = threadIdx.x & 63;
  int tg = threadIdx.x >> 6;
  const float* src = W + (size_t)h * (D_ * HD_) + (size_t)d0 * HD_;
#pragma unroll
  for (int r = 0; r < 16; ++r) {
    int dy = tg * 16 + r;
    tile[tx][dy] = f2bf(src[(size_t)dy * HD_ + tx]);
  }
  __syncthreads();
  unsigned short* dst = W1T + ((size_t)blockIdx.z * 1024 + (size_t)h * 64) * 1024 + d0;
#pragma unroll
  for (int r = 0; r < 16; ++r) {
    int hd = tg * 16 + r;
    dst[(size_t)hd * 1024 + tx] = tile[hd][tx];
  }
}

// ---------- prep: Wp [D][D] -> WpT [n][k] ----------
__global__ void k_wp_t(const float* __restrict__ Wp, unsigned short* __restrict__ WpT) {
  __shared__ unsigned short tile[64][65];
  int n0 = blockIdx.x * 64, k0 = blockIdx.y * 64;
  int tx = threadIdx.x & 63;
  int tg = threadIdx.x >> 6;
#pragma unroll
  for (int r = 0; r < 16; ++r) {
    int ky = tg * 16 + r;
    tile[tx][ky] = f2bf(Wp[(size_t)(k0 + ky) * D_ + n0 + tx]);
  }
  __syncthreads();
#pragma unroll
  for (int r = 0; r < 16; ++r) {
    int ny = tg * 16 + r;
    WpT[(size_t)(n0 + ny) * D_ + k0 + tx] = tile[ny][tx];
  }
}

// ===================== 8-phase staging helpers =====================
// 256 rows x 32 k-half, chunk-of-8 XOR swizzle by (row>>1)&3 (2 loads/thread)
__device__ __forceinline__ void stage_half(const unsigned short* g0, unsigned short* l0, int tid) {
  int r0 = tid >> 2, s0 = tid & 3;
  gload_lds16(g0 + (size_t)r0 * 1024 + ((s0 ^ ((r0 >> 1) & 3)) << 3), l0 + tid * 8);
  int r1 = r0 + 128;
  gload_lds16(g0 + (size_t)r1 * 1024 + ((s0 ^ ((r1 >> 1) & 3)) << 3), l0 + 4096 + tid * 8);
}
// 128 rows x 32 k-half (1 load/thread)
__device__ __forceinline__ void stage_rows128(const unsigned short* g0, unsigned short* l0, int tid) {
  int r0 = tid >> 2, s0 = tid & 3;
  gload_lds16(g0 + (size_t)r0 * 1024 + ((s0 ^ ((r0 >> 1) & 3)) << 3), l0 + tid * 8);
}

__device__ __forceinline__ bf16x8 rd_swz(const unsigned short* base, int row, int g) {
  return *(const bf16x8*)&base[row * 32 + ((g ^ ((row >> 1) & 3)) << 3)];
}

// ===================== 8-phase 256x256 GEMM for q,k =====================
__global__ __launch_bounds__(512, 2) void k_gemm_qk(const unsigned short* __restrict__ xb,
                                                    const unsigned short* __restrict__ W1T,
                                                    unsigned short* __restrict__ qb,
                                                    unsigned short* __restrict__ kb) {
  __shared__ __align__(16) unsigned short As[32768];  // 64 KB
  __shared__ __align__(16) unsigned short Bs[32768];  // 64 KB
  int tid = threadIdx.x;
  int lane = tid & 63;
  int wid = tid >> 6;
  int c = lane & 15, g = lane >> 4;
  int wr = wid >> 2, wc = wid & 3;
  int bid = blockIdx.x;
  int xcd = bid & 7, idx = bid >> 3;
  int by = (xcd << 2) | (idx & 3);
  int bx = idx >> 2;
  int m0 = by << 8, n0 = bx << 8;
  const unsigned short* gA = xb + (size_t)m0 * 1024;
  const unsigned short* gB = W1T + (size_t)n0 * 1024;

  f32x4 acc[8][4];
#pragma unroll
  for (int i = 0; i < 8; ++i)
#pragma unroll
    for (int n = 0; n < 4; ++n) acc[i][n] = (f32x4){0.f, 0.f, 0.f, 0.f};

  stage_half(gA + 0,  As + 0, tid);
  stage_half(gB + 0,  Bs + 0, tid);
  stage_half(gA + 32, As + 8192, tid);
  stage_half(gB + 32, Bs + 8192, tid);

  for (int t = 0; t < 16; ++t) {
    int sl = (t & 1) << 14;
    int so = sl ^ 16384;
    int kn = (t + 1) << 6;
    bool pf = (t < 15);
    const unsigned short* Asl = As + sl;
    const unsigned short* Bsl = Bs + sl;
    bf16x8 bf[4];

    asm volatile("s_waitcnt vmcnt(4)" ::: "memory");
    __builtin_amdgcn_s_barrier();
    if (pf) stage_half(gA + kn, As + so, tid);
#pragma unroll
    for (int n = 0; n < 4; ++n) bf[n] = rd_swz(Bsl, wc * 64 + n * 16 + c, g);
    {
      bf16x8 af[4];
#pragma unroll
      for (int j = 0; j < 4; ++j) af[j] = rd_swz(Asl, wr * 128 + j * 16 + c, g);
      __builtin_amdgcn_s_setprio(1);
#pragma unroll
      for (int j = 0; j < 4; ++j)
#pragma unroll
        for (int n = 0; n < 4; ++n) acc[j][n] = MFMA32(af[j], bf[n], acc[j][n]);
      __builtin_amdgcn_s_setprio(0);
    }
    if (pf) stage_half(gB + kn, Bs + so, tid);
    {
      bf16x8 af[4];
#pragma unroll
      for (int j = 0; j < 4; ++j) af[j] = rd_swz(Asl, wr * 128 + (4 + j) * 16 + c, g);
      __builtin_amdgcn_s_setprio(1);
#pragma unroll
      for (int j = 0; j < 4; ++j)
#pragma unroll
        for (int n = 0; n < 4; ++n) acc[4 + j][n] = MFMA32(af[j], bf[n], acc[4 + j][n]);
      __builtin_amdgcn_s_setprio(0);
    }
    if (pf) asm volatile("s_waitcnt vmcnt(4)" ::: "memory");
    else    asm volatile("s_waitcnt vmcnt(0)" ::: "memory");  // final K-half must be certified
    __builtin_amdgcn_s_barrier();
    if (pf) stage_half(gA + kn + 32, As + so + 8192, tid);
#pragma unroll
    for (int n = 0; n < 4; ++n) bf[n] = rd_swz(Bsl + 8192, wc * 64 + n * 16 + c, g);
    {
      bf16x8 af[4];
#pragma unroll
      for (int j = 0; j < 4; ++j) af[j] = rd_swz(Asl + 8192, wr * 128 + j * 16 + c, g);
      __builtin_amdgcn_s_setprio(1);
#pragma unroll
      for (int j = 0; j < 4; ++j)
#pragma unroll
        for (int n = 0; n < 4; ++n) acc[j][n] = MFMA32(af[j], bf[n], acc[j][n]);
      __builtin_amdgcn_s_setprio(0);
    }
    if (pf) stage_half(gB + kn + 32, Bs + so + 8192, tid);
    {
      bf16x8 af[4];
#pragma unroll
      for (int j = 0; j < 4; ++j) af[j] = rd_swz(Asl + 8192, wr * 128 + (4 + j) * 16 + c, g);
      __builtin_amdgcn_s_setprio(1);
#pragma unroll
      for (int j = 0; j < 4; ++j)
#pragma unroll
        for (int n = 0; n < 4; ++n) acc[4 + j][n] = MFMA32(af[j], bf[n], acc[4 + j][n]);
      __builtin_amdgcn_s_setprio(0);
    }
  }

  // epilogue: q scaled into log2-softmax domain (0.125 * log2(e)); k unscaled
  int Cnb = n0 + wc * 64;
  int qkv = Cnb >> 10;
  int h = (Cnb >> 6) & 15;
  int b = m0 >> 11;
  int s0 = m0 & 2047;
  unsigned short* dst = ((qkv == 0) ? qb : kb) + ((size_t)(b * 16 + h) * S_) * HD_;
  float sc = (qkv == 0) ? 0.18033688011112042f : 1.0f;
#pragma unroll
  for (int mrep = 0; mrep < 8; ++mrep)
#pragma unroll
    for (int n = 0; n < 4; ++n)
#pragma unroll
      for (int r = 0; r < 4; ++r) {
        int s = s0 + wr * 128 + mrep * 16 + 4 * g + r;
        int hd = n * 16 + c;
        dst[(size_t)s * HD_ + hd] = f2bf(acc[mrep][n][r] * sc);
      }
}

// ===================== 8-phase 128x256 GEMM: vt = W1T_v @ xb^T =====================
// A = W1T_v [1024 vrow][1024 k] (128-row tiles), B = xb [8192 (b,s)][1024 k] (256-row tiles)
__global__ __launch_bounds__(512, 2) void k_gemm_vt(const unsigned short* __restrict__ W1T,
                                                    const unsigned short* __restrict__ xb,
                                                    unsigned short* __restrict__ vt) {
  __shared__ __align__(16) unsigned short As[16384];  // [2 slot][2 kh][128*32] 32 KB
  __shared__ __align__(16) unsigned short Bs[32768];  // [2 slot][2 kh][256*32] 64 KB
  int tid = threadIdx.x;
  int lane = tid & 63;
  int wid = tid >> 6;
  int c = lane & 15, g = lane >> 4;
  int wr = wid >> 2, wc = wid & 3;   // wr in 0..1 (m), wc in 0..3 (n)
  int bid = blockIdx.x;
  int by = bid & 7;        // m-tile (8 total) -> XCD owns one m-band
  int bx = bid >> 3;       // n-tile (32)
  int m0 = by << 7, n0 = bx << 8;
  const unsigned short* gA = W1T + (size_t)(2048 + m0) * 1024;  // v-section
  const unsigned short* gB = xb + (size_t)n0 * 1024;

  f32x4 acc[4][4];
#pragma unroll
  for (int m = 0; m < 4; ++m)
#pragma unroll
    for (int n = 0; n < 4; ++n) acc[m][n] = (f32x4){0.f, 0.f, 0.f, 0.f};

  // prologue order: A0, B0, A1, B1 (1+2+1+2 = 6 loads/thread)
  stage_rows128(gA + 0,  As + 0, tid);
  stage_half  (gB + 0,  Bs + 0, tid);
  stage_rows128(gA + 32, As + 4096, tid);
  stage_half  (gB + 32, Bs + 8192, tid);

  for (int t = 0; t < 16; ++t) {
    int slA = (t & 1) << 13, soA = slA ^ 8192;
    int slB = (t & 1) << 14, soB = slB ^ 16384;
    int kn = (t + 1) << 6;
    bool pf = (t < 15);
    const unsigned short* Asl = As + slA;
    const unsigned short* Bsl = Bs + slB;
    bf16x8 af[4];

    // phase0: certify {A0,B0}(t); prefetch A0(t+1); MFMA (nh0, kh0)
    asm volatile("s_waitcnt vmcnt(3)" ::: "memory");
    __builtin_amdgcn_s_barrier();
    if (pf) stage_rows128(gA + kn, As + soA, tid);
#pragma unroll
    for (int j = 0; j < 4; ++j) af[j] = rd_swz(Asl, wr * 64 + j * 16 + c, g);
    {
      bf16x8 bf[2];
#pragma unroll
      for (int n = 0; n < 2; ++n) bf[n] = rd_swz(Bsl, wc * 64 + n * 16 + c, g);
      __builtin_amdgcn_s_setprio(1);
#pragma unroll
      for (int j = 0; j < 4; ++j)
#pragma unroll
        for (int n = 0; n < 2; ++n) acc[j][n] = MFMA32(af[j], bf[n], acc[j][n]);
      __builtin_amdgcn_s_setprio(0);
    }
    // phase1: prefetch B0(t+1); MFMA (nh1, kh0)
    if (pf) stage_half(gB + kn, Bs + soB, tid);
    {
      bf16x8 bf[2];
#pragma unroll
      for (int n = 0; n < 2; ++n) bf[n] = rd_swz(Bsl, wc * 64 + (2 + n) * 16 + c, g);
      __builtin_amdgcn_s_setprio(1);
#pragma unroll
      for (int j = 0; j < 4; ++j)
#pragma unroll
        for (int n = 0; n < 2; ++n) acc[j][2 + n] = MFMA32(af[j], bf[n], acc[j][2 + n]);
      __builtin_amdgcn_s_setprio(0);
    }
    // phase2: certify {A1,B1}(t); prefetch A1(t+1); MFMA (nh0, kh1)
    if (pf) asm volatile("s_waitcnt vmcnt(3)" ::: "memory");
    else    asm volatile("s_waitcnt vmcnt(0)" ::: "memory");
    __builtin_amdgcn_s_barrier();
    if (pf) stage_rows128(gA + kn + 32, As + soA + 4096, tid);
#pragma unroll
    for (int j = 0; j < 4; ++j) af[j] = rd_swz(Asl + 4096, wr * 64 + j * 16 + c, g);
    {
      bf16x8 bf[2];
#pragma unroll
      for (int n = 0; n < 2; ++n) bf[n] = rd_swz(Bsl + 8192, wc * 64 + n * 16 + c, g);
      __builtin_amdgcn_s_setprio(1);
#pragma unroll
      for (int j = 0; j < 4; ++j)
#pragma unroll
        for (int n = 0; n < 2; ++n) acc[j][n] = MFMA32(af[j], bf[n], acc[j][n]);
      __builtin_amdgcn_s_setprio(0);
    }
    // phase3: prefetch B1(t+1); MFMA (nh1, kh1)
    if (pf) stage_half(gB + kn + 32, Bs + soB + 8192, tid);
    {
      bf16x8 bf[2];
#pragma unroll
      for (int n = 0; n < 2; ++n) bf[n] = rd_swz(Bsl + 8192, wc * 64 + (2 + n) * 16 + c, g);
      __builtin_amdgcn_s_setprio(1);
#pragma unroll
      for (int j = 0; j < 4; ++j)
#pragma unroll
        for (int n = 0; n < 2; ++n) acc[j][2 + n] = MFMA32(af[j], bf[n], acc[j][2 + n]);
      __builtin_amdgcn_s_setprio(0);
    }
  }

  // epilogue: C[vrow][N] -> vt[(b*1024+vrow)*2048 + s], lanes span s (coalesced 32B)
#pragma unroll
  for (int m = 0; m < 4; ++m)
#pragma unroll
    for (int n = 0; n < 4; ++n)
#pragma unroll
      for (int r = 0; r < 4; ++r) {
        int vrow = m0 + wr * 64 + m * 16 + 4 * g + r;
        int N = n0 + wc * 64 + n * 16 + c;
        int b = N >> 11, s = N & 2047;
        vt[((size_t)(b << 10) + vrow) * S_ + s] = f2bf(acc[m][n][r]);
      }
}

// ===================== 8-phase 256x128 GEMM: out = at @ Wp + bp =====================
// A = at [8192][1024] (256-row tiles), B = WpT [1024 n][1024 k] (128-row tiles)
__global__ __launch_bounds__(512, 2) void k_gemm_out(const unsigned short* __restrict__ at,
                                                     const unsigned short* __restrict__ WpT,
                                                     const float* __restrict__ bp,
                                                     float* __restrict__ out) {
  __shared__ __align__(16) unsigned short As[32768];  // [2][2][256*32] 64 KB
  __shared__ __align__(16) unsigned short Bs[16384];  // [2][2][128*32] 32 KB
  int tid = threadIdx.x;
  int lane = tid & 63;
  int wid = tid >> 6;
  int c = lane & 15, g = lane >> 4;
  int wr = wid >> 2, wc = wid & 3;   // wr in 0..1 (m: 128 rows each), wc 0..3 (n: 32 each)
  int bid = blockIdx.x;
  int xcd = bid & 7, idx = bid >> 3;
  int by = (xcd << 2) | (idx & 3);   // 32 m-tiles
  int bx = idx >> 2;                 // 8 n-tiles
  int m0 = by << 8, n0 = bx << 7;
  const unsigned short* gA = at + (size_t)m0 * 1024;
  const unsigned short* gB = WpT + (size_t)n0 * 1024;

  f32x4 acc[8][2];
#pragma unroll
  for (int i = 0; i < 8; ++i)
#pragma unroll
    for (int n = 0; n < 2; ++n) acc[i][n] = (f32x4){0.f, 0.f, 0.f, 0.f};

  // prologue order: A0(2), B0(1), A1(2), B1(1)
  stage_half   (gA + 0,  As + 0, tid);
  stage_rows128(gB + 0,  Bs + 0, tid);
  stage_half   (gA + 32, As + 8192, tid);
  stage_rows128(gB + 32, Bs + 4096, tid);

  for (int t = 0; t < 16; ++t) {
    int slA = (t & 1) << 14, soA = slA ^ 16384;
    int slB = (t & 1) << 13, soB = slB ^ 8192;
    int kn = (t + 1) << 6;
    bool pf = (t < 15);
    const unsigned short* Asl = As + slA;
    const unsigned short* Bsl = Bs + slB;
    bf16x8 bf[2];

    // phase0: certify {A0,B0}(t); prefetch A0(t+1); MFMA (mq0, kh0)
    asm volatile("s_waitcnt vmcnt(3)" ::: "memory");
    __builtin_amdgcn_s_barrier();
    if (pf) stage_half(gA + kn, As + soA, tid);
#pragma unroll
    for (int n = 0; n < 2; ++n) bf[n] = rd_swz(Bsl, wc * 32 + n * 16 + c, g);
    {
      bf16x8 af[4];
#pragma unroll
      for (int j = 0; j < 4; ++j) af[j] = rd_swz(Asl, wr * 128 + j * 16 + c, g);
      __builtin_amdgcn_s_setprio(1);
#pragma unroll
      for (int j = 0; j < 4; ++j)
#pragma unroll
        for (int n = 0; n < 2; ++n) acc[j][n] = MFMA32(af[j], bf[n], acc[j][n]);
      __builtin_amdgcn_s_setprio(0);
    }
    // phase1: prefetch B0(t+1); MFMA (mq1, kh0)
    if (pf) stage_rows128(gB + kn, Bs + soB, tid);
    {
      bf16x8 af[4];
#pragma unroll
      for (int j = 0; j < 4; ++j) af[j] = rd_swz(Asl, wr * 128 + (4 + j) * 16 + c, g);
      __builtin_amdgcn_s_setprio(1);
#pragma unroll
      for (int j = 0; j < 4; ++j)
#pragma unroll
        for (int n = 0; n < 2; ++n) acc[4 + j][n] = MFMA32(af[j], bf[n], acc[4 + j][n]);
      __builtin_amdgcn_s_setprio(0);
    }
    // phase2: certify {A1,B1}(t); prefetch A1(t+1); MFMA (mq0, kh1)
    if (pf) asm volatile("s_waitcnt vmcnt(3)" ::: "memory");
    else    asm volatile("s_waitcnt vmcnt(0)" ::: "memory");
    __builtin_amdgcn_s_barrier();
    if (pf) stage_half(gA + kn + 32, As + soA + 8192, tid);
#pragma unroll
    for (int n = 0; n < 2; ++n) bf[n] = rd_swz(Bsl + 4096, wc * 32 + n * 16 + c, g);
    {
      bf16x8 af[4];
#pragma unroll
      for (int j = 0; j < 4; ++j) af[j] = rd_swz(Asl + 8192, wr * 128 + j * 16 + c, g);
      __builtin_amdgcn_s_setprio(1);
#pragma unroll
      for (int j = 0; j < 4; ++j)
#pragma unroll
        for (int n = 0; n < 2; ++n) acc[j][n] = MFMA32(af[j], bf[n], acc[j][n]);
      __builtin_amdgcn_s_setprio(0);
    }
    // phase3: prefetch B1(t+1); MFMA (mq1, kh1)
    if (pf) stage_rows128(gB + kn + 32, Bs + soB + 4096, tid);
    {
      bf16x8 af[4];
#pragma unroll
      for (int j = 0; j < 4; ++j) af[j] = rd_swz(Asl + 8192, wr * 128 + (4 + j) * 16 + c, g);
      __builtin_amdgcn_s_setprio(1);
#pragma unroll
      for (int j = 0; j < 4; ++j)
#pragma unroll
        for (int n = 0; n < 2; ++n) acc[4 + j][n] = MFMA32(af[j], bf[n], acc[4 + j][n]);
      __builtin_amdgcn_s_setprio(0);
    }
  }

#pragma unroll
  for (int mrep = 0; mrep < 8; ++mrep)
#pragma unroll
    for (int n = 0; n < 2; ++n)
#pragma unroll
      for (int r = 0; r < 4; ++r) {
        int R = m0 + wr * 128 + mrep * 16 + 4 * g + r;
        int Cn = n0 + wc * 32 + n * 16 + c;
        out[(size_t)R * D_ + Cn] = acc[mrep][n][r] + bp[Cn];
      }
}

// ---------- attention staging helper: K/V tile -> swizzled LDS ----------
__device__ __forceinline__ void stage_kv(const unsigned short* kp, const unsigned short* vp,
                                         int tb, unsigned short* Ks, unsigned short* Vs,
                                         int tid) {
  int i0 = tid, i1 = tid + 256;
  int r0 = i0 >> 3, ch0 = ((i0 & 7) ^ (r0 & 7)) << 3;
  int r1 = i1 >> 3, ch1 = ((i1 & 7) ^ (r1 & 7)) << 3;
  gload_lds16(kp + (size_t)(tb + r0) * HD_ + ch0, &Ks[i0 * 8]);
  gload_lds16(kp + (size_t)(tb + r1) * HD_ + ch1, &Ks[i1 * 8]);
  gload_lds16(vp + (size_t)r0 * S_ + tb + ch0, &Vs[i0 * 8]);
  gload_lds16(vp + (size_t)r1 * S_ + tb + ch1, &Vs[i1 * 8]);
}

// ---------- flash attention v6c: R11 structure + precomputed LDS offsets + v_perm pack ----------
__global__ __launch_bounds__(256) void k_attn(const unsigned short* __restrict__ qb,
                                              const unsigned short* __restrict__ kb,
                                              const unsigned short* __restrict__ vt,
                                              unsigned short* __restrict__ attn) {
  __shared__ __align__(16) unsigned short Ks[2][64 * 64];
  __shared__ __align__(16) unsigned short Vs[2][64 * 64];
  int tid = threadIdx.x;
  int lane = tid & 63;
  int w = tid >> 6;
  int c = lane & 15, g = lane >> 4;
  int bid = blockIdx.x;
  int xcd = bid & 7, idx = bid >> 3;      // idx 0..127
  int bh = (xcd << 3) | (idx & 7);        // 8 bh per XCD
  int j = 15 - (idx >> 3);                // long blocks dispatched first
  const unsigned short* kp = kb + (size_t)bh * S_ * HD_;
  const unsigned short* vp = vt + (size_t)bh * HD_ * S_;
  int b = bh >> 4, h = bh & 15;

  // loop-invariant LDS element offsets
  int koff[4][2], voff[4][2][2];
#pragma unroll
  for (int k4 = 0; k4 < 4; ++k4) {
    int row = k4 * 16 + c, rx = row & 7;
    koff[k4][0] = row * 64 + ((g ^ rx) << 3);
    koff[k4][1] = row * 64 + (((4 + g) ^ rx) << 3);
  }
#pragma unroll
  for (int c4 = 0; c4 < 4; ++c4) {
    int row = c4 * 16 + c, rx = row & 7;
#pragma unroll
    for (int ks = 0; ks < 2; ++ks) {
      int e0 = ks * 32 + 4 * g;
      int e1 = e0 + 16;
      voff[c4][ks][0] = row * 64 + ((((e0 >> 3) ^ rx) << 3) | (e0 & 7));
      voff[c4][ks][1] = row * 64 + ((((e1 >> 3) ^ rx) << 3) | (e1 & 7));
    }
  }

  int q0w = j * 128 + w * 32;
  const unsigned short* qp = qb + ((size_t)bh * S_ + q0w) * HD_;
  bf16x8 qf[2][2];
#pragma unroll
  for (int qs = 0; qs < 2; ++qs)
#pragma unroll
    for (int h2 = 0; h2 < 2; ++h2)
      qf[qs][h2] = *(const bf16x8*)(qp + (size_t)(qs * 16 + c) * HD_ + h2 * 32 + 8 * g);

  const f32x4 fz = {0.f, 0.f, 0.f, 0.f};
  f32x4 oacc[4][2];
#pragma unroll
  for (int c4 = 0; c4 < 4; ++c4)
#pragma unroll
    for (int qs = 0; qs < 2; ++qs) oacc[c4][qs] = fz;
  float m[2] = {-1e30f, -1e30f};
  float l[2] = {0.f, 0.f};

  int nkb = 2 * j + 2;
  int nkw = (q0w + 95) >> 6;

  stage_kv(kp, vp, 0, Ks[0], Vs[0], tid);
  __syncthreads();

  for (int kt = 0; kt < nkb; ++kt) {
    int cur = kt & 1;
    if (kt + 1 < nkb) stage_kv(kp, vp, (kt + 1) << 6, Ks[cur ^ 1], Vs[cur ^ 1], tid);
    if (kt < nkw) {
      int tb = kt << 6;
      const unsigned short* KsC = Ks[cur];
      const unsigned short* VsC = Vs[cur];
      // ---- QK^T: S^T[t][q] (log2 domain; q pre-scaled by 0.125*log2e) ----
      f32x4 st[4][2];
#pragma unroll
      for (int k4 = 0; k4 < 4; ++k4) {
        bf16x8 a0 = *(const bf16x8*)&KsC[koff[k4][0]];
        bf16x8 a1 = *(const bf16x8*)&KsC[koff[k4][1]];
#pragma unroll
        for (int qs = 0; qs < 2; ++qs) {
          f32x4 t0 = MFMA32(a0, qf[qs][0], fz);
          st[k4][qs] = MFMA32(a1, qf[qs][1], t0);
        }
      }
      if (tb + 63 > q0w) {  // causal mask near diagonal
#pragma unroll
        for (int k4 = 0; k4 < 4; ++k4)
#pragma unroll
          for (int qs = 0; qs < 2; ++qs)
#pragma unroll
            for (int r = 0; r < 4; ++r)
              if (tb + k4 * 16 + 4 * g + r > q0w + qs * 16 + c) st[k4][qs][r] = -1e30f;
      }
      // ---- online softmax (base 2) with defer-max ----
      bf16x8 pa[2][2];
#pragma unroll
      for (int qs = 0; qs < 2; ++qs) {
        float mx = -1e30f;
#pragma unroll
        for (int k4 = 0; k4 < 4; ++k4)
#pragma unroll
          for (int r = 0; r < 4; ++r) mx = fmaxf(mx, st[k4][qs][r]);
        mx = fmaxf(mx, __shfl_xor(mx, 16));
        mx = fmaxf(mx, __shfl_xor(mx, 32));
        if (!__all(mx - m[qs] <= 8.f)) {
          float m_new = fmaxf(m[qs], mx);
          float resc = fexp2(m[qs] - m_new);
          m[qs] = m_new;
          float rb0 = __shfl(resc, 4 * g + 0);
          float rb1 = __shfl(resc, 4 * g + 1);
          float rb2 = __shfl(resc, 4 * g + 2);
          float rb3 = __shfl(resc, 4 * g + 3);
#pragma unroll
          for (int c4 = 0; c4 < 4; ++c4) {
            oacc[c4][qs][0] *= rb0; oacc[c4][qs][1] *= rb1;
            oacc[c4][qs][2] *= rb2; oacc[c4][qs][3] *= rb3;
          }
          l[qs] *= resc;
        }
        float mh = m[qs];
        float rs = 0.f;
#pragma unroll
        for (int k4 = 0; k4 < 4; ++k4)
#pragma unroll
          for (int r = 0; r < 4; ++r) {
            float e = fexp2(st[k4][qs][r] - mh);
            st[k4][qs][r] = e;
            rs += e;
          }
        rs += __shfl_xor(rs, 16);
        rs += __shfl_xor(rs, 32);
        l[qs] += rs;
#pragma unroll
        for (int ks = 0; ks < 2; ++ks) {
          union { uint32_t wd[4]; bf16x8 v; } pu;
          int ks2 = ks * 2;
          pu.wd[0] = pk2(st[ks2][qs][0], st[ks2][qs][1]);
          pu.wd[1] = pk2(st[ks2][qs][2], st[ks2][qs][3]);
          pu.wd[2] = pk2(st[ks2 + 1][qs][0], st[ks2 + 1][qs][1]);
          pu.wd[3] = pk2(st[ks2 + 1][qs][2], st[ks2 + 1][qs][3]);
          pa[qs][ks] = pu.v;
        }
      }
      // ---- PV ----
#pragma unroll
      for (int c4 = 0; c4 < 4; ++c4) {
#pragma unroll
        for (int ks = 0; ks < 2; ++ks) {
          bf16x4 v0 = *(const bf16x4*)&VsC[voff[c4][ks][0]];
          bf16x4 v1 = *(const bf16x4*)&VsC[voff[c4][ks][1]];
          bf16x8 vf;
          vf[0] = v0[0]; vf[1] = v0[1]; vf[2] = v0[2]; vf[3] = v0[3];
          vf[4] = v1[0]; vf[5] = v1[1]; vf[6] = v1[2]; vf[7] = v1[3];
#pragma unroll
          for (int qs = 0; qs < 2; ++qs)
            oacc[c4][qs] = MFMA32(pa[qs][ks], vf, oacc[c4][qs]);
        }
      }
    }
    __syncthreads();
  }
  // ---- epilogue ----
#pragma unroll
  for (int qs = 0; qs < 2; ++qs) {
    float linv = 1.f / l[qs];
    float lb0 = __shfl(linv, 4 * g + 0);
    float lb1 = __shfl(linv, 4 * g + 1);
    float lb2 = __shfl(linv, 4 * g + 2);
    float lb3 = __shfl(linv, 4 * g + 3);
    float lb[4] = {lb0, lb1, lb2, lb3};
    unsigned short* op = attn + ((size_t)b * S_ + q0w + qs * 16) * D_ + h * HD_;
#pragma unroll
    for (int c4 = 0; c4 < 4; ++c4)
#pragma unroll
      for (int r = 0; r < 4; ++r)
        op[(size_t)(4 * g + r) * D_ + c4 * 16 + c] = f2bf(oacc[c4][qs][r] * lb[r]);
  }
}

extern "C" void kernel_launch(void* const* d_in, const int* in_sizes, int n_in,
                              void* d_out, int out_size, void* d_ws, size_t ws_size,
                              hipStream_t stream) {
  const float* x  = (const float*)d_in[0];
  const float* Wq = (const float*)d_in[1];
  const float* Wk = (const float*)d_in[2];
  const float* Wv = (const float*)d_in[3];
  const float* Wp = (const float*)d_in[4];
  const float* bp = (const float*)d_in[5];
  float* out = (float*)d_out;
  char* ws = (char*)d_ws;
  unsigned short* xb  = (unsigned short*)(ws);                       // 16 MB (reused as attn out)
  unsigned short* w1t = (unsigned short*)(ws + (size_t)(16u << 20)); //  6 MB
  unsigned short* wpt = (unsigned short*)(ws + (size_t)(22u << 20)); //  2 MB
  unsigned short* qb  = (unsigned short*)(ws + (size_t)(24u << 20)); // 16 MB
  unsigned short* kb  = (unsigned short*)(ws + (size_t)(40u << 20)); // 16 MB
  unsigned short* vt  = (unsigned short*)(ws + (size_t)(56u << 20)); // 16 MB
  unsigned short* at  = xb;  // xb dead after q/k/v gemms; reuse for attention output

  k_cast_x<<<dim3(4096), dim3(256), 0, stream>>>(x, xb);
  k_wqkv_t<<<dim3(16, 16, 3), dim3(256), 0, stream>>>(Wq, Wk, Wv, w1t);
  k_wp_t<<<dim3(16, 16), dim3(256), 0, stream>>>(Wp, wpt);
  k_gemm_qk<<<dim3(256), dim3(512), 0, stream>>>(xb, w1t, qb, kb);
  k_gemm_vt<<<dim3(256), dim3(512), 0, stream>>>(w1t, xb, vt);
  k_attn<<<dim3(1024), dim3(256), 0, stream>>>(qb, kb, vt, at);
  k_gemm_out<<<dim3(256), dim3(512), 0, stream>>>(at, wpt, bp, out);
}

// Round 13
// 177.182 us; speedup vs baseline: 1.0951x; 1.0951x over previous
//
#include <hip/hip_runtime.h>
#include <stdint.h>

#define B_  4
#define S_  2048
#define D_  1024
#define H_  16
#define HD_ 64

typedef __attribute__((ext_vector_type(8))) short bf16x8;
typedef __attribute__((ext_vector_type(4))) short bf16x4;
typedef __attribute__((ext_vector_type(4))) float f32x4;

#define MFMA32(a, b, c) __builtin_amdgcn_mfma_f32_16x16x32_bf16(a, b, c, 0, 0, 0)

__device__ __forceinline__ unsigned short f2bf(float f) {
  union { float f; uint32_t u; } cv; cv.f = f;
  uint32_t x = cv.u;
  uint32_t r = (x + 0x7fffu + ((x >> 16) & 1u)) >> 16;  // RNE
  return (unsigned short)r;
}

__device__ __forceinline__ float fexp2(float x) {
#if __has_builtin(__builtin_amdgcn_exp2f)
  return __builtin_amdgcn_exp2f(x);   // native v_exp_f32 (2^x)
#else
  return exp2f(x);
#endif
}

// pack two f32 -> two bf16 (truncate) in one v_perm_b32
__device__ __forceinline__ uint32_t pk2(float lo, float hi) {
  union { float f; uint32_t u; } a, b;
  a.f = lo; b.f = hi;
#if __has_builtin(__builtin_amdgcn_perm)
  return __builtin_amdgcn_perm(b.u, a.u, 0x07060302u);
#else
  return (b.u & 0xffff0000u) | (a.u >> 16);
#endif
}

__device__ __forceinline__ void gload_lds16(const unsigned short* g, unsigned short* l) {
  __builtin_amdgcn_global_load_lds((const __attribute__((address_space(1))) void*)g,
                                   (__attribute__((address_space(3))) void*)l, 16, 0, 0);
}

// ---------- prep: x fp32 -> bf16 ----------
__global__ void k_cast_x(const float* __restrict__ x, unsigned short* __restrict__ xb) {
  size_t i = ((size_t)blockIdx.x * 256 + threadIdx.x) * 8;
  float4 a = *(const float4*)(x + i);
  float4 b = *(const float4*)(x + i + 4);
  bf16x8 o;
  o[0] = (short)f2bf(a.x); o[1] = (short)f2bf(a.y);
  o[2] = (short)f2bf(a.z); o[3] = (short)f2bf(a.w);
  o[4] = (short)f2bf(b.x); o[5] = (short)f2bf(b.y);
  o[6] = (short)f2bf(b.z); o[7] = (short)f2bf(b.w);
  *(bf16x8*)(xb + i) = o;
}

// ---------- prep: Wq/Wk/Wv [H,D,HD] -> W1T [3072][1024] ----------
__global__ void k_wqkv_t(const float* __restrict__ Wq, const float* __restrict__ Wk,
                         const float* __restrict__ Wv, unsigned short* __restrict__ W1T) {
  __shared__ unsigned short tile[64][65];
  const float* W = (blockIdx.z == 0) ? Wq : (blockIdx.z == 1) ? Wk : Wv;
  int h = blockIdx.y;
  int d0 = blockIdx.x * 64;
  int tx = threadIdx.x & 63;
  int tg = threadIdx.x >> 6;
  const float* src = W + (size_t)h * (D_ * HD_) + (size_t)d0 * HD_;
#pragma unroll
  for (int r = 0; r < 16; ++r) {
    int dy = tg * 16 + r;
    tile[tx][dy] = f2bf(src[(size_t)dy * HD_ + tx]);
  }
  __syncthreads();
  unsigned short* dst = W1T + ((size_t)blockIdx.z * 1024 + (size_t)h * 64) * 1024 + d0;
#pragma unroll
  for (int r = 0; r < 16; ++r) {
    int hd = tg * 16 + r;
    dst[(size_t)hd * 1024 + tx] = tile[hd][tx];
  }
}

// ---------- prep: Wp [D][D] -> WpT [n][k] ----------
__global__ void k_wp_t(const float* __restrict__ Wp, unsigned short* __restrict__ WpT) {
  __shared__ unsigned short tile[64][65];
  int n0 = blockIdx.x * 64, k0 = blockIdx.y * 64;
  int tx = threadIdx.x & 63;
  int tg = threadIdx.x >> 6;
#pragma unroll
  for (int r = 0; r < 16; ++r) {
    int ky = tg * 16 + r;
    tile[tx][ky] = f2bf(Wp[(size_t)(k0 + ky) * D_ + n0 + tx]);
  }
  __syncthreads();
#pragma unroll
  for (int r = 0; r < 16; ++r) {
    int ny = tg * 16 + r;
    WpT[(size_t)(n0 + ny) * D_ + k0 + tx] = tile[ny][tx];
  }
}

// ===================== 8-phase staging helpers =====================
__device__ __forceinline__ void stage_half(const unsigned short* g0, unsigned short* l0, int tid) {
  int r0 = tid >> 2, s0 = tid & 3;
  gload_lds16(g0 + (size_t)r0 * 1024 + ((s0 ^ ((r0 >> 1) & 3)) << 3), l0 + tid * 8);
  int r1 = r0 + 128;
  gload_lds16(g0 + (size_t)r1 * 1024 + ((s0 ^ ((r1 >> 1) & 3)) << 3), l0 + 4096 + tid * 8);
}

__device__ __forceinline__ bf16x8 rd_swz(const unsigned short* base, int row, int g) {
  return *(const bf16x8*)&base[row * 32 + ((g ^ ((row >> 1) & 3)) << 3)];
}

// ===================== 8-phase 256x256 GEMM for q,k =====================
__global__ __launch_bounds__(512, 2) void k_gemm_qk(const unsigned short* __restrict__ xb,
                                                    const unsigned short* __restrict__ W1T,
                                                    unsigned short* __restrict__ qb,
                                                    unsigned short* __restrict__ kb) {
  __shared__ __align__(16) unsigned short As[32768];  // 64 KB
  __shared__ __align__(16) unsigned short Bs[32768];  // 64 KB
  int tid = threadIdx.x;
  int lane = tid & 63;
  int wid = tid >> 6;
  int c = lane & 15, g = lane >> 4;
  int wr = wid >> 2, wc = wid & 3;
  int bid = blockIdx.x;
  int xcd = bid & 7, idx = bid >> 3;
  int by = (xcd << 2) | (idx & 3);
  int bx = idx >> 2;
  int m0 = by << 8, n0 = bx << 8;
  const unsigned short* gA = xb + (size_t)m0 * 1024;
  const unsigned short* gB = W1T + (size_t)n0 * 1024;

  f32x4 acc[8][4];
#pragma unroll
  for (int i = 0; i < 8; ++i)
#pragma unroll
    for (int n = 0; n < 4; ++n) acc[i][n] = (f32x4){0.f, 0.f, 0.f, 0.f};

  stage_half(gA + 0,  As + 0, tid);
  stage_half(gB + 0,  Bs + 0, tid);
  stage_half(gA + 32, As + 8192, tid);
  stage_half(gB + 32, Bs + 8192, tid);

  for (int t = 0; t < 16; ++t) {
    int sl = (t & 1) << 14;
    int so = sl ^ 16384;
    int kn = (t + 1) << 6;
    bool pf = (t < 15);
    const unsigned short* Asl = As + sl;
    const unsigned short* Bsl = Bs + sl;
    bf16x8 bf[4];

    asm volatile("s_waitcnt vmcnt(4)" ::: "memory");
    __builtin_amdgcn_s_barrier();
    if (pf) stage_half(gA + kn, As + so, tid);
#pragma unroll
    for (int n = 0; n < 4; ++n) bf[n] = rd_swz(Bsl, wc * 64 + n * 16 + c, g);
    {
      bf16x8 af[4];
#pragma unroll
      for (int j = 0; j < 4; ++j) af[j] = rd_swz(Asl, wr * 128 + j * 16 + c, g);
      __builtin_amdgcn_s_setprio(1);
#pragma unroll
      for (int j = 0; j < 4; ++j)
#pragma unroll
        for (int n = 0; n < 4; ++n) acc[j][n] = MFMA32(af[j], bf[n], acc[j][n]);
      __builtin_amdgcn_s_setprio(0);
    }
    if (pf) stage_half(gB + kn, Bs + so, tid);
    {
      bf16x8 af[4];
#pragma unroll
      for (int j = 0; j < 4; ++j) af[j] = rd_swz(Asl, wr * 128 + (4 + j) * 16 + c, g);
      __builtin_amdgcn_s_setprio(1);
#pragma unroll
      for (int j = 0; j < 4; ++j)
#pragma unroll
        for (int n = 0; n < 4; ++n) acc[4 + j][n] = MFMA32(af[j], bf[n], acc[4 + j][n]);
      __builtin_amdgcn_s_setprio(0);
    }
    if (pf) asm volatile("s_waitcnt vmcnt(4)" ::: "memory");
    else    asm volatile("s_waitcnt vmcnt(0)" ::: "memory");  // final K-half certified
    __builtin_amdgcn_s_barrier();
    if (pf) stage_half(gA + kn + 32, As + so + 8192, tid);
#pragma unroll
    for (int n = 0; n < 4; ++n) bf[n] = rd_swz(Bsl + 8192, wc * 64 + n * 16 + c, g);
    {
      bf16x8 af[4];
#pragma unroll
      for (int j = 0; j < 4; ++j) af[j] = rd_swz(Asl + 8192, wr * 128 + j * 16 + c, g);
      __builtin_amdgcn_s_setprio(1);
#pragma unroll
      for (int j = 0; j < 4; ++j)
#pragma unroll
        for (int n = 0; n < 4; ++n) acc[j][n] = MFMA32(af[j], bf[n], acc[j][n]);
      __builtin_amdgcn_s_setprio(0);
    }
    if (pf) stage_half(gB + kn + 32, Bs + so + 8192, tid);
    {
      bf16x8 af[4];
#pragma unroll
      for (int j = 0; j < 4; ++j) af[j] = rd_swz(Asl + 8192, wr * 128 + (4 + j) * 16 + c, g);
      __builtin_amdgcn_s_setprio(1);
#pragma unroll
      for (int j = 0; j < 4; ++j)
#pragma unroll
        for (int n = 0; n < 4; ++n) acc[4 + j][n] = MFMA32(af[j], bf[n], acc[4 + j][n]);
      __builtin_amdgcn_s_setprio(0);
    }
  }

  // epilogue: q scaled into log2-softmax domain (0.125 * log2(e)); k unscaled
  int Cnb = n0 + wc * 64;
  int qkv = Cnb >> 10;
  int h = (Cnb >> 6) & 15;
  int b = m0 >> 11;
  int s0 = m0 & 2047;
  unsigned short* dst = ((qkv == 0) ? qb : kb) + ((size_t)(b * 16 + h) * S_) * HD_;
  float sc = (qkv == 0) ? 0.18033688011112042f : 1.0f;
#pragma unroll
  for (int mrep = 0; mrep < 8; ++mrep)
#pragma unroll
    for (int n = 0; n < 4; ++n)
#pragma unroll
      for (int r = 0; r < 4; ++r) {
        int s = s0 + wr * 128 + mrep * 16 + 4 * g + r;
        int hd = n * 16 + c;
        dst[(size_t)s * HD_ + hd] = f2bf(acc[mrep][n][r] * sc);
      }
}

// ===================== GEMM: vt[1024][8192] = W1T_v @ xb^T (m97 128^2) ==========
__global__ __launch_bounds__(256) void k_gemm_vt(const unsigned short* __restrict__ W1T,
                                                 const unsigned short* __restrict__ xb,
                                                 unsigned short* __restrict__ vt) {
  __shared__ __align__(16) unsigned short As[128 * 32];
  __shared__ __align__(16) unsigned short Bs[128 * 32];
  const int K = 1024;
  int tid = threadIdx.x;
  int lane = tid & 63;
  int w = tid >> 6;
  int c = lane & 15, g = lane >> 4;
  int wr = w >> 1, wc = w & 1;
  int nwg = gridDim.x * gridDim.y;
  int bid = blockIdx.y * gridDim.x + blockIdx.x;
  int swzb = (bid & 7) * (nwg >> 3) + (bid >> 3);
  int bx = swzb % gridDim.x, by = swzb / gridDim.x;
  int m0 = by * 128;   // v-row (h,hd), M=1024
  int n0 = bx * 128;   // (b,s),       N=8192
  const unsigned short* Av = W1T + (size_t)2048 * 1024;  // v-section
  f32x4 acc[4][4];
#pragma unroll
  for (int m = 0; m < 4; ++m)
#pragma unroll
    for (int n = 0; n < 4; ++n) acc[m][n] = (f32x4){0.f, 0.f, 0.f, 0.f};

  int t0 = tid, t1 = tid + 256;
  const unsigned short* ga0 = Av + (size_t)(m0 + (t0 >> 2)) * K + 8 * (t0 & 3);
  const unsigned short* ga1 = Av + (size_t)(m0 + (t1 >> 2)) * K + 8 * (t1 & 3);
  const unsigned short* gb0 = xb + (size_t)(n0 + (t0 >> 2)) * K + 8 * (t0 & 3);
  const unsigned short* gb1 = xb + (size_t)(n0 + (t1 >> 2)) * K + 8 * (t1 & 3);

  for (int kk = 0; kk < K; kk += 32) {
    __syncthreads();
    gload_lds16(ga0 + kk, &As[t0 * 8]);
    gload_lds16(ga1 + kk, &As[t1 * 8]);
    gload_lds16(gb0 + kk, &Bs[t0 * 8]);
    gload_lds16(gb1 + kk, &Bs[t1 * 8]);
    __syncthreads();
    bf16x8 af[4], bfr[4];
#pragma unroll
    for (int m = 0; m < 4; ++m)
      af[m] = *(const bf16x8*)&As[(wr * 64 + m * 16 + c) * 32 + 8 * g];
#pragma unroll
    for (int n = 0; n < 4; ++n)
      bfr[n] = *(const bf16x8*)&Bs[(wc * 64 + n * 16 + c) * 32 + 8 * g];
#pragma unroll
    for (int m = 0; m < 4; ++m)
#pragma unroll
      for (int n = 0; n < 4; ++n) acc[m][n] = MFMA32(af[m], bfr[n], acc[m][n]);
  }

  int b = (n0 >> 11);
#pragma unroll
  for (int m = 0; m < 4; ++m)
#pragma unroll
    for (int n = 0; n < 4; ++n)
#pragma unroll
      for (int r = 0; r < 4; ++r) {
        int vm = m0 + wr * 64 + m * 16 + 4 * g + r;
        int Cn = n0 + wc * 64 + n * 16 + c;
        int s = Cn & 2047;
        vt[((size_t)(b << 10) + vm) * S_ + s] = f2bf(acc[m][n][r]);
      }
}

// ---------- attention staging helper: K/V tile -> swizzled LDS ----------
__device__ __forceinline__ void stage_kv(const unsigned short* kp, const unsigned short* vp,
                                         int tb, unsigned short* Ks, unsigned short* Vs,
                                         int tid) {
  int i0 = tid, i1 = tid + 256;
  int r0 = i0 >> 3, ch0 = ((i0 & 7) ^ (r0 & 7)) << 3;
  int r1 = i1 >> 3, ch1 = ((i1 & 7) ^ (r1 & 7)) << 3;
  gload_lds16(kp + (size_t)(tb + r0) * HD_ + ch0, &Ks[i0 * 8]);
  gload_lds16(kp + (size_t)(tb + r1) * HD_ + ch1, &Ks[i1 * 8]);
  gload_lds16(vp + (size_t)r0 * S_ + tb + ch0, &Vs[i0 * 8]);
  gload_lds16(vp + (size_t)r1 * S_ + tb + ch1, &Vs[i1 * 8]);
}

// ---------- flash attention v7: R11 structure + deferred-l (per-lane partial sums,
// one cross-lane reduce in epilogue) ----------
__global__ __launch_bounds__(256) void k_attn(const unsigned short* __restrict__ qb,
                                              const unsigned short* __restrict__ kb,
                                              const unsigned short* __restrict__ vt,
                                              unsigned short* __restrict__ attn) {
  __shared__ __align__(16) unsigned short Ks[2][64 * 64];
  __shared__ __align__(16) unsigned short Vs[2][64 * 64];
  int tid = threadIdx.x;
  int lane = tid & 63;
  int w = tid >> 6;
  int c = lane & 15, g = lane >> 4;
  int bid = blockIdx.x;
  int xcd = bid & 7, idx = bid >> 3;      // idx 0..127
  int bh = (xcd << 3) | (idx & 7);        // 8 bh per XCD
  int j = 15 - (idx >> 3);                // long blocks dispatched first
  const unsigned short* kp = kb + (size_t)bh * S_ * HD_;
  const unsigned short* vp = vt + (size_t)bh * HD_ * S_;
  int b = bh >> 4, h = bh & 15;

  // loop-invariant LDS element offsets
  int koff[4][2], voff[4][2][2];
#pragma unroll
  for (int k4 = 0; k4 < 4; ++k4) {
    int row = k4 * 16 + c, rx = row & 7;
    koff[k4][0] = row * 64 + ((g ^ rx) << 3);
    koff[k4][1] = row * 64 + (((4 + g) ^ rx) << 3);
  }
#pragma unroll
  for (int c4 = 0; c4 < 4; ++c4) {
    int row = c4 * 16 + c, rx = row & 7;
#pragma unroll
    for (int ks = 0; ks < 2; ++ks) {
      int e0 = ks * 32 + 4 * g;
      int e1 = e0 + 16;
      voff[c4][ks][0] = row * 64 + ((((e0 >> 3) ^ rx) << 3) | (e0 & 7));
      voff[c4][ks][1] = row * 64 + ((((e1 >> 3) ^ rx) << 3) | (e1 & 7));
    }
  }

  int q0w = j * 128 + w * 32;
  const unsigned short* qp = qb + ((size_t)bh * S_ + q0w) * HD_;
  bf16x8 qf[2][2];
#pragma unroll
  for (int qs = 0; qs < 2; ++qs)
#pragma unroll
    for (int h2 = 0; h2 < 2; ++h2)
      qf[qs][h2] = *(const bf16x8*)(qp + (size_t)(qs * 16 + c) * HD_ + h2 * 32 + 8 * g);

  const f32x4 fz = {0.f, 0.f, 0.f, 0.f};
  f32x4 oacc[4][2];
#pragma unroll
  for (int c4 = 0; c4 < 4; ++c4)
#pragma unroll
    for (int qs = 0; qs < 2; ++qs) oacc[c4][qs] = fz;
  float m[2] = {-1e30f, -1e30f};
  float l[2] = {0.f, 0.f};   // per-lane PARTIAL sums (lane's t-subset); reduced in epilogue

  int nkb = 2 * j + 2;
  int nkw = (q0w + 95) >> 6;

  stage_kv(kp, vp, 0, Ks[0], Vs[0], tid);
  __syncthreads();

  for (int kt = 0; kt < nkb; ++kt) {
    int cur = kt & 1;
    if (kt + 1 < nkb) stage_kv(kp, vp, (kt + 1) << 6, Ks[cur ^ 1], Vs[cur ^ 1], tid);
    if (kt < nkw) {
      int tb = kt << 6;
      const unsigned short* KsC = Ks[cur];
      const unsigned short* VsC = Vs[cur];
      // ---- QK^T: S^T[t][q] (log2 domain; q pre-scaled by 0.125*log2e) ----
      f32x4 st[4][2];
#pragma unroll
      for (int k4 = 0; k4 < 4; ++k4) {
        bf16x8 a0 = *(const bf16x8*)&KsC[koff[k4][0]];
        bf16x8 a1 = *(const bf16x8*)&KsC[koff[k4][1]];
#pragma unroll
        for (int qs = 0; qs < 2; ++qs) {
          f32x4 t0 = MFMA32(a0, qf[qs][0], fz);
          st[k4][qs] = MFMA32(a1, qf[qs][1], t0);
        }
      }
      if (tb + 63 > q0w) {  // causal mask near diagonal
#pragma unroll
        for (int k4 = 0; k4 < 4; ++k4)
#pragma unroll
          for (int qs = 0; qs < 2; ++qs)
#pragma unroll
            for (int r = 0; r < 4; ++r)
              if (tb + k4 * 16 + 4 * g + r > q0w + qs * 16 + c) st[k4][qs][r] = -1e30f;
      }
      // ---- online softmax (base 2), defer-max, deferred-l ----
      bf16x8 pa[2][2];
#pragma unroll
      for (int qs = 0; qs < 2; ++qs) {
        float mx = -1e30f;
#pragma unroll
        for (int k4 = 0; k4 < 4; ++k4)
#pragma unroll
          for (int r = 0; r < 4; ++r) mx = fmaxf(mx, st[k4][qs][r]);
        mx = fmaxf(mx, __shfl_xor(mx, 16));
        mx = fmaxf(mx, __shfl_xor(mx, 32));
        if (!__all(mx - m[qs] <= 8.f)) {
          float m_new = fmaxf(m[qs], mx);
          float resc = fexp2(m[qs] - m_new);
          m[qs] = m_new;
          float rb0 = __shfl(resc, 4 * g + 0);
          float rb1 = __shfl(resc, 4 * g + 1);
          float rb2 = __shfl(resc, 4 * g + 2);
          float rb3 = __shfl(resc, 4 * g + 3);
#pragma unroll
          for (int c4 = 0; c4 < 4; ++c4) {
            oacc[c4][qs][0] *= rb0; oacc[c4][qs][1] *= rb1;
            oacc[c4][qs][2] *= rb2; oacc[c4][qs][3] *= rb3;
          }
          l[qs] *= resc;   // same resc across the q-group -> partials stay consistent
        }
        float mh = m[qs];
        float rs = 0.f;
#pragma unroll
        for (int k4 = 0; k4 < 4; ++k4)
#pragma unroll
          for (int r = 0; r < 4; ++r) {
            float e = fexp2(st[k4][qs][r] - mh);
            st[k4][qs][r] = e;
            rs += e;
          }
        l[qs] += rs;       // per-lane partial; cross-lane reduce deferred to epilogue
#pragma unroll
        for (int ks = 0; ks < 2; ++ks) {
          union { uint32_t wd[4]; bf16x8 v; } pu;
          int ks2 = ks * 2;
          pu.wd[0] = pk2(st[ks2][qs][0], st[ks2][qs][1]);
          pu.wd[1] = pk2(st[ks2][qs][2], st[ks2][qs][3]);
          pu.wd[2] = pk2(st[ks2 + 1][qs][0], st[ks2 + 1][qs][1]);
          pu.wd[3] = pk2(st[ks2 + 1][qs][2], st[ks2 + 1][qs][3]);
          pa[qs][ks] = pu.v;
        }
      }
      // ---- PV ----
#pragma unroll
      for (int c4 = 0; c4 < 4; ++c4) {
#pragma unroll
        for (int ks = 0; ks < 2; ++ks) {
          bf16x4 v0 = *(const bf16x4*)&VsC[voff[c4][ks][0]];
          bf16x4 v1 = *(const bf16x4*)&VsC[voff[c4][ks][1]];
          bf16x8 vf;
          vf[0] = v0[0]; vf[1] = v0[1]; vf[2] = v0[2]; vf[3] = v0[3];
          vf[4] = v1[0]; vf[5] = v1[1]; vf[6] = v1[2]; vf[7] = v1[3];
#pragma unroll
          for (int qs = 0; qs < 2; ++qs)
            oacc[c4][qs] = MFMA32(pa[qs][ks], vf, oacc[c4][qs]);
        }
      }
    }
    __syncthreads();
  }
  // ---- epilogue: single cross-lane l reduction per qs ----
#pragma unroll
  for (int qs = 0; qs < 2; ++qs) {
    float lt = l[qs];
    lt += __shfl_xor(lt, 16);
    lt += __shfl_xor(lt, 32);
    float linv = 1.f / lt;
    float lb0 = __shfl(linv, 4 * g + 0);
    float lb1 = __shfl(linv, 4 * g + 1);
    float lb2 = __shfl(linv, 4 * g + 2);
    float lb3 = __shfl(linv, 4 * g + 3);
    float lb[4] = {lb0, lb1, lb2, lb3};
    unsigned short* op = attn + ((size_t)b * S_ + q0w + qs * 16) * D_ + h * HD_;
#pragma unroll
    for (int c4 = 0; c4 < 4; ++c4)
#pragma unroll
      for (int r = 0; r < 4; ++r)
        op[(size_t)(4 * g + r) * D_ + c4 * 16 + c] = f2bf(oacc[c4][qs][r] * lb[r]);
  }
}

// ---------- GEMM2: out[8192][1024] = attn @ Wp + bp (fp32 out, m97 128^2) ----------
__global__ __launch_bounds__(256) void k_gemm_out(const unsigned short* __restrict__ at,
                                                  const unsigned short* __restrict__ WpT,
                                                  const float* __restrict__ bp,
                                                  float* __restrict__ out) {
  __shared__ __align__(16) unsigned short As[128 * 32];
  __shared__ __align__(16) unsigned short Bs[128 * 32];
  const int K = 1024;
  int tid = threadIdx.x;
  int lane = tid & 63;
  int w = tid >> 6;
  int c = lane & 15, g = lane >> 4;
  int wr = w >> 1, wc = w & 1;
  int nwg = gridDim.x * gridDim.y;
  int bid = blockIdx.y * gridDim.x + blockIdx.x;
  int swzb = (bid & 7) * (nwg >> 3) + (bid >> 3);
  int bx = swzb % gridDim.x, by = swzb / gridDim.x;
  int m0 = by * 128;
  int n0 = bx * 128;
  f32x4 acc[4][4];
#pragma unroll
  for (int m = 0; m < 4; ++m)
#pragma unroll
    for (int n = 0; n < 4; ++n) acc[m][n] = (f32x4){0.f, 0.f, 0.f, 0.f};

  int t0 = tid, t1 = tid + 256;
  const unsigned short* ga0 = at + (size_t)(m0 + (t0 >> 2)) * K + 8 * (t0 & 3);
  const unsigned short* ga1 = at + (size_t)(m0 + (t1 >> 2)) * K + 8 * (t1 & 3);
  const unsigned short* gb0 = WpT + (size_t)(n0 + (t0 >> 2)) * K + 8 * (t0 & 3);
  const unsigned short* gb1 = WpT + (size_t)(n0 + (t1 >> 2)) * K + 8 * (t1 & 3);

  for (int kk = 0; kk < K; kk += 32) {
    __syncthreads();
    gload_lds16(ga0 + kk, &As[t0 * 8]);
    gload_lds16(ga1 + kk, &As[t1 * 8]);
    gload_lds16(gb0 + kk, &Bs[t0 * 8]);
    gload_lds16(gb1 + kk, &Bs[t1 * 8]);
    __syncthreads();
    bf16x8 af[4], bfr[4];
#pragma unroll
    for (int m = 0; m < 4; ++m)
      af[m] = *(const bf16x8*)&As[(wr * 64 + m * 16 + c) * 32 + 8 * g];
#pragma unroll
    for (int n = 0; n < 4; ++n)
      bfr[n] = *(const bf16x8*)&Bs[(wc * 64 + n * 16 + c) * 32 + 8 * g];
#pragma unroll
    for (int m = 0; m < 4; ++m)
#pragma unroll
      for (int n = 0; n < 4; ++n) acc[m][n] = MFMA32(af[m], bfr[n], acc[m][n]);
  }

#pragma unroll
  for (int m = 0; m < 4; ++m)
#pragma unroll
    for (int n = 0; n < 4; ++n)
#pragma unroll
      for (int r = 0; r < 4; ++r) {
        int R = m0 + wr * 64 + m * 16 + 4 * g + r;
        int Cn = n0 + wc * 64 + n * 16 + c;
        out[(size_t)R * D_ + Cn] = acc[m][n][r] + bp[Cn];
      }
}

extern "C" void kernel_launch(void* const* d_in, const int* in_sizes, int n_in,
                              void* d_out, int out_size, void* d_ws, size_t ws_size,
                              hipStream_t stream) {
  const float* x  = (const float*)d_in[0];
  const float* Wq = (const float*)d_in[1];
  const float* Wk = (const float*)d_in[2];
  const float* Wv = (const float*)d_in[3];
  const float* Wp = (const float*)d_in[4];
  const float* bp = (const float*)d_in[5];
  float* out = (float*)d_out;
  char* ws = (char*)d_ws;
  unsigned short* xb  = (unsigned short*)(ws);                       // 16 MB (reused as attn out)
  unsigned short* w1t = (unsigned short*)(ws + (size_t)(16u << 20)); //  6 MB
  unsigned short* wpt = (unsigned short*)(ws + (size_t)(22u << 20)); //  2 MB
  unsigned short* qb  = (unsigned short*)(ws + (size_t)(24u << 20)); // 16 MB
  unsigned short* kb  = (unsigned short*)(ws + (size_t)(40u << 20)); // 16 MB
  unsigned short* vt  = (unsigned short*)(ws + (size_t)(56u << 20)); // 16 MB
  unsigned short* at  = xb;  // xb dead after q/k/v gemms; reuse for attention output

  k_cast_x<<<dim3(4096), dim3(256), 0, stream>>>(x, xb);
  k_wqkv_t<<<dim3(16, 16, 3), dim3(256), 0, stream>>>(Wq, Wk, Wv, w1t);
  k_wp_t<<<dim3(16, 16), dim3(256), 0, stream>>>(Wp, wpt);
  k_gemm_qk<<<dim3(256), dim3(512), 0, stream>>>(xb, w1t, qb, kb);
  k_gemm_vt<<<dim3(64, 8), dim3(256), 0, stream>>>(w1t, xb, vt);
  k_attn<<<dim3(1024), dim3(256), 0, stream>>>(qb, kb, vt, at);
  k_gemm_out<<<dim3(8, 64), dim3(256), 0, stream>>>(at, wpt, bp, out);
}